// Round 13
// baseline (165.361 us; speedup 1.0000x reference)
//
#include <hip/hip_runtime.h>
#include <math.h>

typedef unsigned short u16;
typedef unsigned int u32;
typedef __attribute__((ext_vector_type(8))) short s8v;   // 8 bf16 (4 VGPRs)
typedef __attribute__((ext_vector_type(4))) float f4v;   // MFMA acc

#define KNBR 32
#define MFMA16(a, b, c) __builtin_amdgcn_mfma_f32_16x16x32_bf16((a), (b), (c), 0, 0, 0)

__device__ __forceinline__ float bf2f(u16 u) { return __uint_as_float((u32)u << 16); }
__device__ __forceinline__ float bflo(u32 u) { return __uint_as_float(u << 16); }
__device__ __forceinline__ float bfhi(u32 u) { return __uint_as_float(u & 0xffff0000u); }
__device__ __forceinline__ u16 f2bf(float f) {
    u32 u = __float_as_uint(f);
    return (u16)((u + 0x7fffu + ((u >> 16) & 1u)) >> 16);
}
__device__ __forceinline__ u32 pk2(float a, float b) {
    return (u32)f2bf(a) | ((u32)f2bf(b) << 16);
}
__device__ __forceinline__ float leaky(float v) { return v >= 0.f ? v : 0.1f * v; }
__device__ __forceinline__ float sigm(float v) { return 1.f / (1.f + expf(-v)); }

__device__ __forceinline__ int swz_plb(int b, int full) {
    if (!full) return b << 6;
    int xcd = b & 7;
    int within = ((b >> 3) << 1) | (xcd & 1);
    return ((xcd >> 1) << 13) + (within << 6);
}

// Pre-packed B-frag tables (u32 words, offsets from TB):
#define T2O 8704
#define T3O 13056
#define T4O 17664
#define T5O 22272
#define T6O 24576
#define TTOT 26880

__global__ __launch_bounds__(512) void k_prep(
    const float* __restrict__ W1f, const float* __restrict__ W2f,
    const float* __restrict__ W3f, u32* __restrict__ TB)
{
    int id = blockIdx.x * 512 + threadIdx.x;
    if (id >= TTOT) return;
    u32 word = 0;
    if (id < T2O) {                      // T1: W1 g0,g1 [2][64][68]
        int g = id / 4352, r = id - g * 4352;
        int n = r / 68, kp = r - n * 68;
        if (kp < 64)
            word = pk2(W1f[g * 8384 + kp * 128 + n], W1f[g * 8384 + kp * 128 + 64 + n]);
    } else if (id < T3O) {               // T2: W1 g2 [64][68]
        int r = id - T2O;
        int n = r / 68, kp = r - n * 68;
        if (kp < 64)
            word = pk2(W1f[16768 + kp * 128 + n], W1f[16768 + kp * 128 + 64 + n]);
    } else if (id < T4O) {               // T3: W2 g0,g1 [2][64][36]
        int r = id - T3O;
        int g = r / 2304, r2 = r - g * 2304;
        int n = r2 / 36, kp = r2 - n * 36;
        if (kp < 32)
            word = pk2(W2f[g * 4096 + kp * 128 + n], W2f[g * 4096 + kp * 128 + 64 + n]);
    } else if (id < T5O) {               // T4: W3 g0,g1
        int r = id - T4O;
        int g = r / 2304, r2 = r - g * 2304;
        int n = r2 / 36, kp = r2 - n * 36;
        if (kp < 32)
            word = pk2(W3f[g * 4096 + kp * 128 + n], W3f[g * 4096 + kp * 128 + 64 + n]);
    } else if (id < T6O) {               // T5: W2 g2
        int r = id - T5O;
        int n = r / 36, kp = r - n * 36;
        if (kp < 32)
            word = pk2(W2f[8192 + kp * 128 + n], W2f[8192 + kp * 128 + 64 + n]);
    } else {                             // T6: W3 g2
        int r = id - T6O;
        int n = r / 36, kp = r - n * 36;
        if (kp < 32)
            word = pk2(W3f[8192 + kp * 128 + n], W3f[8192 + kp * 128 + 64 + n]);
    }
    TB[id] = word;
}

// EP record per local point: 64 u32 words.
// [0..15]  k2 -> (row_even | row_odd<<16)  (rows local to the pass)
// [16..47] uint2 per k2: pk2(e0_e,e1_e), pk2(e0_o,e1_o)
// [48..63] k2 -> pk2(e2_e, e2_o)
__global__ __launch_bounds__(256) void k_prep_edges(
    const int* __restrict__ nidx, const float* __restrict__ ef,
    u32* __restrict__ EP, int p0, int full)
{
    int tid = blockIdx.x * 256 + threadIdx.x;
    int ptl = tid >> 4, k2 = tid & 15;
    int ptg = p0 + ptl;
    int2 nn = *(const int2*)(nidx + (size_t)ptg * KNBR + 2 * k2);
    int rb = full ? ((ptg >> 13) << 13) : 0;
    u32 idxw = (u32)(rb + nn.x) | ((u32)(rb + nn.y) << 16);
    const float* e = ef + ((size_t)ptg * KNBR + 2 * k2) * 3;
    float2 a = *(const float2*)(e);
    float2 b = *(const float2*)(e + 2);
    float2 c = *(const float2*)(e + 4);
    u32* row = EP + (size_t)ptl * 64;
    row[k2] = idxw;
    ((uint2*)(row + 16))[k2] = make_uint2(pk2(a.x, a.y), pk2(b.y, c.x));
    row[48 + k2] = pk2(b.x, c.y);
}

// MFMA frags: A[m=lane&15][k=quad*8+j]; B[k=quad*8+j][n=lane&15];
// D: col(n)=lane&15, row(m)=quad*4+reg.

// ---------------- K_A: P01 = [h|x] @ W1[0,1] + b1 (1024 thr, 16 waves) ----------------
__global__ __launch_bounds__(1024) void k_gemm_p01(
    const float* __restrict__ h, const float* __restrict__ x,
    const u32* __restrict__ TB, const float* __restrict__ b1f,
    u32* __restrict__ P01, int p0, int full)
{
    __shared__ u32 a_lds[64 * 68];      // 17408 B
    __shared__ u32 wb[8704];            // 34816 B -> 52224 total
    int t = threadIdx.x;
    int plb = swz_plb(blockIdx.x, full);
    int pgb = p0 + plb;
    for (int i = 0; i < 4; ++i) {
        int id = t + i * 1024;
        int p = id >> 6, cw = id & 63;
        const float* src = (cw < 32) ? (h + (size_t)(pgb + p) * 64 + cw * 2)
                                     : (x + (size_t)(pgb + p) * 64 + (cw - 32) * 2);
        float2 v = *(const float2*)src;
        a_lds[p * 68 + cw] = pk2(v.x, v.y);
    }
    for (int i = 0; i < 9; ++i) {
        int id = t + i * 1024;
        if (id < 8704) wb[id] = TB[id];
    }
    __syncthreads();
    int lane = t & 63;
    int w = __builtin_amdgcn_readfirstlane(t >> 6);   // 0..15
    int m = w & 3, nt = w >> 2;                       // m-tile, n-tile (per gate)
    int quad = lane >> 4, l15 = lane & 15;
    f4v acc0, acc1;
    {
        float b0 = b1f[nt * 16 + l15];
        float b1 = b1f[64 + nt * 16 + l15];
        acc0 = (f4v){b0, b0, b0, b0};
        acc1 = (f4v){b1, b1, b1, b1};
    }
    #pragma unroll
    for (int kb = 0; kb < 4; ++kb) {
        s8v af = *(const s8v*)&a_lds[(m * 16 + l15) * 68 + kb * 16 + quad * 4];
        s8v bf0 = *(const s8v*)&wb[(nt * 16 + l15) * 68 + kb * 16 + quad * 4];
        s8v bf1 = *(const s8v*)&wb[(64 + nt * 16 + l15) * 68 + kb * 16 + quad * 4];
        acc0 = MFMA16(af, bf0, acc0);
        acc1 = MFMA16(af, bf1, acc1);
    }
    #pragma unroll
    for (int r = 0; r < 4; ++r) {
        int pt = m * 16 + quad * 4 + r;
        P01[(size_t)(plb + pt) * 64 + nt * 16 + l15] = pk2(acc0[r], acc1[r]);
    }
}

// ---------------- K_B: pool01 + MLP(g0,g1) + gemm_p2 (1024 thr) ----------------
__global__ __launch_bounds__(1024) void k_fuse01(
    const u32* __restrict__ P01, const float* __restrict__ W1f,
    const u32* __restrict__ TB, const u32* __restrict__ EP,
    const float* __restrict__ h, const float* __restrict__ x,
    const float* __restrict__ b1f, const float* __restrict__ b2f,
    const float* __restrict__ b3f,
    u16* __restrict__ Z, float* __restrict__ P2, int p0, int full)
{
    __shared__ u32 a_lds[64 * 68];      // 17408 B
    __shared__ u32 wb[4608];            // 18432 B
    __shared__ u32 ep_l[64 * 64];       // 16384 B -> 52224 total
    int t = threadIdx.x;
    int plb = swz_plb(blockIdx.x, full);
    int pg0 = p0 + plb;
    int lane = t & 63;
    int w = __builtin_amdgcn_readfirstlane(t >> 6);   // 0..15
    int quad = lane >> 4, l15 = lane & 15;
    u16* y16 = (u16*)a_lds;

    for (int i = 0; i < 5; ++i) {       // W2 frags (4608)
        int id = t + i * 1024;
        if (id < 4608) wb[id] = TB[T3O + id];
    }
    for (int i = 0; i < 4; ++i) {       // EP copy (4096 words, coalesced)
        int id = t + i * 1024;
        ep_l[id] = EP[(size_t)plb * 64 + id];
    }
    __syncthreads();
    {   // pool: wave pools 4 points (lane = channel)
        float w00 = W1f[8192 + lane], w01 = W1f[8256 + lane], w02 = W1f[8320 + lane];
        float w10 = W1f[16576 + lane], w11 = W1f[16640 + lane], w12 = W1f[16704 + lane];
        const u32* P01l = P01 + lane;
        for (int pp = 0; pp < 4; ++pp) {
            int lp = w * 4 + pp;
            const u32* ib = &ep_l[lp * 64];
            float m0 = -1e30f, m1 = -1e30f;
            #pragma unroll
            for (int k2 = 0; k2 < 16; ++k2) {
                u32 rw = ib[k2];
                uint2 ew = ((const uint2*)(ib + 16))[k2];
                u32 e2w = ib[48 + k2];
                u32 g0 = P01l[(rw & 0xffffu) * 64];
                u32 g1 = P01l[(rw >> 16) * 64];
                float e00 = bflo(ew.x), e01 = bfhi(ew.x), e02 = bflo(e2w);
                float e10 = bflo(ew.y), e11 = bfhi(ew.y), e12 = bfhi(e2w);
                m0 = fmaxf(m0, bflo(g0) + e00 * w00 + e01 * w01 + e02 * w02);
                m1 = fmaxf(m1, bfhi(g0) + e00 * w10 + e01 * w11 + e02 * w12);
                m0 = fmaxf(m0, bflo(g1) + e10 * w00 + e11 * w01 + e12 * w02);
                m1 = fmaxf(m1, bfhi(g1) + e10 * w10 + e11 * w11 + e12 * w12);
            }
            y16[lp * 136 + lane]      = f2bf(leaky(m0));
            y16[lp * 136 + 64 + lane] = f2bf(leaky(m1));
        }
    }
    __syncthreads();
    int m = w & 3, c = w >> 2, g = c >> 1, np = c & 1;
    f4v acc[2];
    #pragma unroll
    for (int nt = 0; nt < 2; ++nt) {
        float b = b2f[g * 64 + (np * 2 + nt) * 16 + l15];
        acc[nt] = (f4v){b, b, b, b};
    }
    #pragma unroll
    for (int kb = 0; kb < 2; ++kb) {     // L1
        s8v af = *(const s8v*)&a_lds[(m * 16 + l15) * 68 + g * 32 + kb * 16 + quad * 4];
        #pragma unroll
        for (int nt = 0; nt < 2; ++nt) {
            s8v bf = *(const s8v*)&wb[(g * 64 + (np * 2 + nt) * 16 + l15) * 36
                                      + kb * 16 + quad * 4];
            acc[nt] = MFMA16(af, bf, acc[nt]);
        }
    }
    __syncthreads();                     // all L1 A-reads done before t overwrites Y
    #pragma unroll
    for (int nt = 0; nt < 2; ++nt)
        #pragma unroll
        for (int r = 0; r < 4; ++r)
            y16[(m * 16 + quad * 4 + r) * 136 + g * 64 + (np * 2 + nt) * 16 + l15] =
                f2bf(leaky(acc[nt][r]));
    for (int i = 0; i < 5; ++i) {        // W3 frags
        int id = t + i * 1024;
        if (id < 4608) wb[id] = TB[T4O + id];
    }
    __syncthreads();
    #pragma unroll
    for (int nt = 0; nt < 2; ++nt) {
        float b = b3f[g * 64 + (np * 2 + nt) * 16 + l15];
        acc[nt] = (f4v){b, b, b, b};
    }
    #pragma unroll
    for (int kb = 0; kb < 2; ++kb) {     // L2
        s8v af = *(const s8v*)&a_lds[(m * 16 + l15) * 68 + g * 32 + kb * 16 + quad * 4];
        #pragma unroll
        for (int nt = 0; nt < 2; ++nt) {
            s8v bf = *(const s8v*)&wb[(g * 64 + (np * 2 + nt) * 16 + l15) * 36
                                      + kb * 16 + quad * 4];
            acc[nt] = MFMA16(af, bf, acc[nt]);
        }
    }
    __syncthreads();                     // all L2 reads done
    if (g == 0) {                        // Z -> global
        #pragma unroll
        for (int nt = 0; nt < 2; ++nt)
            #pragma unroll
            for (int r = 0; r < 4; ++r) {
                int pt = m * 16 + quad * 4 + r;
                int ch = (np * 2 + nt) * 16 + l15;
                Z[(size_t)(plb + pt) * 64 + ch] = f2bf(sigm(acc[nt][r]));
            }
    } else {                             // RH -> a_lds words 0..31
        #pragma unroll
        for (int nt = 0; nt < 2; ++nt)
            #pragma unroll
            for (int r = 0; r < 4; ++r) {
                int pt = m * 16 + quad * 4 + r;
                int ch = (np * 2 + nt) * 16 + l15;
                float hv = h[(size_t)(pg0 + pt) * 64 + ch];
                y16[pt * 136 + ch] = f2bf(sigm(acc[nt][r]) * hv);
            }
    }
    for (int i = 0; i < 2; ++i) {        // x -> words 32..63
        int id = t + i * 1024;
        int p = id >> 5, cw = id & 31;
        float2 v = *(const float2*)(x + (size_t)(pg0 + p) * 64 + cw * 2);
        a_lds[p * 68 + 32 + cw] = pk2(v.x, v.y);
    }
    for (int i = 0; i < 5; ++i) {        // W1[2] frags (4352)
        int id = t + i * 1024;
        if (id < 4352) wb[id] = TB[T2O + id];
    }
    __syncthreads();
    int n = w >> 2;                      // gemm_p2: wave = (m, n-tile)
    f4v pacc;
    {
        float b = b1f[128 + n * 16 + l15];
        pacc = (f4v){b, b, b, b};
    }
    #pragma unroll
    for (int kb = 0; kb < 4; ++kb) {     // K=128 ([RH|x])
        s8v af = *(const s8v*)&a_lds[(m * 16 + l15) * 68 + kb * 16 + quad * 4];
        s8v bf = *(const s8v*)&wb[(n * 16 + l15) * 68 + kb * 16 + quad * 4];
        pacc = MFMA16(af, bf, pacc);
    }
    #pragma unroll
    for (int r = 0; r < 4; ++r) {
        int pt = m * 16 + quad * 4 + r;
        P2[(size_t)(plb + pt) * 64 + n * 16 + l15] = pacc[r];
    }
}

// ---------------- K_C: pool2 + MLP(g2) + GRU epilogue (1024 thr) ----------------
__global__ __launch_bounds__(1024) void k_fuse2(
    const float* __restrict__ P2, const float* __restrict__ W1f,
    const u32* __restrict__ TB, const u32* __restrict__ EP,
    const float* __restrict__ b2f, const float* __restrict__ b3f,
    const float* __restrict__ h, const u16* __restrict__ Z,
    float* __restrict__ out, int p0, int full)
{
    __shared__ u32 a_lds[64 * 36];      // 9216 B
    __shared__ u32 wb[2304];            // 9216 B
    __shared__ u32 ep_l[64 * 64];       // 16384 B -> 34816 total
    int t = threadIdx.x;
    int plb = swz_plb(blockIdx.x, full);
    int pg0 = p0 + plb;
    int lane = t & 63;
    int w = __builtin_amdgcn_readfirstlane(t >> 6);
    int quad = lane >> 4, l15 = lane & 15;
    u16* y16 = (u16*)a_lds;

    for (int i = 0; i < 3; ++i) {        // W2[2] frags (2304)
        int id = t + i * 1024;
        if (id < 2304) wb[id] = TB[T5O + id];
    }
    for (int i = 0; i < 4; ++i) {
        int id = t + i * 1024;
        ep_l[id] = EP[(size_t)plb * 64 + id];
    }
    __syncthreads();
    {   // pool2: wave pools 4 points
        const float* W = W1f + 2 * 8384;
        float w0 = W[8192 + lane], w1 = W[8256 + lane], w2 = W[8320 + lane];
        const float* P2l = P2 + lane;
        for (int pp = 0; pp < 4; ++pp) {
            int lp = w * 4 + pp;
            const u32* ib = &ep_l[lp * 64];
            float m = -1e30f;
            #pragma unroll
            for (int k2 = 0; k2 < 16; ++k2) {
                u32 rw = ib[k2];
                uint2 ew = ((const uint2*)(ib + 16))[k2];
                u32 e2w = ib[48 + k2];
                float g0 = P2l[(rw & 0xffffu) * 64];
                float g1 = P2l[(rw >> 16) * 64];
                float e00 = bflo(ew.x), e01 = bfhi(ew.x), e02 = bflo(e2w);
                float e10 = bflo(ew.y), e11 = bfhi(ew.y), e12 = bfhi(e2w);
                m = fmaxf(m, g0 + e00 * w0 + e01 * w1 + e02 * w2);
                m = fmaxf(m, g1 + e10 * w0 + e11 * w1 + e12 * w2);
            }
            y16[lp * 72 + lane] = f2bf(leaky(m));
        }
    }
    __syncthreads();
    int m = w & 3, n = w >> 2;
    f4v acc;
    {
        float b = b2f[128 + n * 16 + l15];
        acc = (f4v){b, b, b, b};
    }
    #pragma unroll
    for (int kb = 0; kb < 2; ++kb) {     // L1
        s8v af = *(const s8v*)&a_lds[(m * 16 + l15) * 36 + kb * 16 + quad * 4];
        s8v bf = *(const s8v*)&wb[(n * 16 + l15) * 36 + kb * 16 + quad * 4];
        acc = MFMA16(af, bf, acc);
    }
    __syncthreads();                     // all L1 A-reads done
    #pragma unroll
    for (int r = 0; r < 4; ++r)
        y16[(m * 16 + quad * 4 + r) * 72 + n * 16 + l15] = f2bf(leaky(acc[r]));
    for (int i = 0; i < 3; ++i) {        // W3[2] frags
        int id = t + i * 1024;
        if (id < 2304) wb[id] = TB[T6O + id];
    }
    __syncthreads();
    {
        float b = b3f[128 + n * 16 + l15];
        acc = (f4v){b, b, b, b};
    }
    #pragma unroll
    for (int kb = 0; kb < 2; ++kb) {     // L2
        s8v af = *(const s8v*)&a_lds[(m * 16 + l15) * 36 + kb * 16 + quad * 4];
        s8v bf = *(const s8v*)&wb[(n * 16 + l15) * 36 + kb * 16 + quad * 4];
        acc = MFMA16(af, bf, acc);
    }
    #pragma unroll
    for (int r = 0; r < 4; ++r) {
        int pt = m * 16 + quad * 4 + r;
        int ch = n * 16 + l15;
        int pl = plb + pt;
        int pg = p0 + pl;
        float z = bf2f(Z[(size_t)pl * 64 + ch]);
        float hv = h[(size_t)pg * 64 + ch];
        out[(size_t)pg * 64 + ch] = (1.f - z) * hv + z * tanhf(acc[r]);
    }
}

extern "C" void kernel_launch(void* const* d_in, const int* in_sizes, int n_in,
                              void* d_out, int out_size, void* d_ws, size_t ws_size,
                              hipStream_t stream)
{
    const float* h  = (const float*)d_in[0];
    const float* x  = (const float*)d_in[1];
    // d_in[2] = c (unused by the reference)
    const float* W1 = (const float*)d_in[3];
    const float* b1 = (const float*)d_in[4];
    const float* W2 = (const float*)d_in[5];
    const float* b2 = (const float*)d_in[6];
    const float* W3 = (const float*)d_in[7];
    const float* b3 = (const float*)d_in[8];
    const int* nidx = (const int*)d_in[9];
    const float* ef = (const float*)d_in[10];
    float* out = (float*)d_out;

    char* wsb = (char*)d_ws;
    size_t need_full = 32768ull * 896ull + (size_t)TTOT * 4ull;
    size_t PN = (ws_size >= need_full) ? 32768 : 8192;
    int passes = (int)(32768 / PN);
    int full = (PN == 32768) ? 1 : 0;

    u32* P01  = (u32*)wsb;                  // [PN][64] u32
    u16* Z    = (u16*)(wsb + PN * 256);     // [PN][64] bf16
    float* P2 = (float*)(wsb + PN * 384);   // [PN][64] f32
    u32* EP   = (u32*)(wsb + PN * 640);     // [PN][64] packed edge/idx records
    u32* TB   = (u32*)(wsb + PN * 896);     // weight-frag tables

    k_prep<<<dim3((TTOT + 511) / 512), 512, 0, stream>>>(W1, W2, W3, TB);
    for (int s = 0; s < passes; ++s) {
        int p0 = (int)(s * PN);
        dim3 g((unsigned)(PN / 64));
        k_prep_edges<<<dim3((unsigned)(PN * 16 / 256)), 256, 0, stream>>>(nidx, ef, EP, p0, full);
        k_gemm_p01<<<g, 1024, 0, stream>>>(h, x, TB, b1, P01, p0, full);
        k_fuse01  <<<g, 1024, 0, stream>>>(P01, W1, TB, EP, h, x,
                                           b1, b2, b3, Z, P2, p0, full);
        k_fuse2   <<<g, 1024, 0, stream>>>(P2, W1, TB, EP,
                                           b2, b3, h, Z, out, p0, full);
    }
}